// Round 14
// baseline (12.687 us; speedup 1.0000x reference)
//
#include <hip/hip_runtime.h>
#include <math.h>

#define RES 128
#define TOPK 16
#define NPTS 192
#define NQ 64                    // 4 tasks * 16 points
#define SIGMA_F (6.0f / 128.0f)
#define NTHR 512                 // 8 waves; waves 0-3 rank (3 elems/thread)

// ---------------------------------------------------------------------------
// Analytic separable IoU (validated exact-to-threshold R11-R13):
//   I  = KI * sum_{batch,q,q'} w_q w_q' exp(-|pa-pb|^2/(4 sigma^2)),
//   KI = sigma^3 pi^1.5 / (Dx*Dy*Dz);  S1+S2 = KI * 2^1.5 * sum_t W_t
//   U = S1+S2-I+1e-5 ;  loss = 1 - I/U
// R14 change: rank waves = 4 (wave == task), 3 elements per thread -> the 48
// uniform ds_read_b128 broadcasts are amortized over 3 ranks (DS-pipe instrs
// 576 -> 192; R13 model says DS was the ~2.9us dominant term). 512 threads =
// exactly 1 cross pair per thread in phase D.
// Strict-rank + deterministic tie repair as validated in R13 (same-thread
// double ties trace idempotent under the same repair rule).
// task: 0 = set1/b0, 1 = set1/b1, 2 = set2/b0, 3 = set2/b1
// ---------------------------------------------------------------------------
__global__ __launch_bounds__(NTHR) void iou_analytic(
    const float* __restrict__ pts1, const float* __restrict__ w1,
    const float* __restrict__ pts2, const float* __restrict__ w2,
    float* __restrict__ out)
{
    __shared__ __align__(16) float swall[4][NPTS];   // 3 KB staged weights
    __shared__ float sval[4][TOPK];
    __shared__ int   sidx[4][TOPK];
    __shared__ __align__(16) float sp4[NQ][4];       // xyz + pad
    __shared__ float sw[NQ];
    __shared__ float sW[4];          // per-task sum of renormalized weights
    __shared__ float sbound[6];      // lo x,y,z ; hi x,y,z
    __shared__ float rP[8];

    const int tid  = threadIdx.x;
    const int lane = tid & 63;
    const int wid  = tid >> 6;       // 0..7

    // ---- phase A: stage all 4x192=768 weights -> LDS (<=2 loads/thread) ---
    #pragma unroll
    for (int e = tid; e < 4 * NPTS; e += NTHR) {
        const int t  = e / NPTS;
        const int el = e - t * NPTS;
        const float* __restrict__ src = (t >= 2 ? w2 : w1) + (t & 1) * NPTS;
        swall[t][el] = src[el];
    }
    __syncthreads();

    // ---- phase B: strict rank, waves 0-3, 3 elements per thread ----
    int r0 = 0, r1 = 0, r2 = 0;
    float v0 = 0.0f, v1 = 0.0f, v2 = 0.0f;
    const float* __restrict__ pt = nullptr;
    if (wid < 4) {
        const int task = wid;
        pt = (task >= 2 ? pts2 : pts1) + (task & 1) * NPTS * 3;
        v0 = swall[task][lane];
        v1 = swall[task][lane + 64];
        v2 = swall[task][lane + 128];
        const float4* __restrict__ wrow = (const float4*)swall[task];
        #pragma unroll
        for (int c = 0; c < NPTS / 4; ++c) {
            const float4 wv = wrow[c];   // uniform addr per wave -> broadcast
            r0 += (wv.x > v0) + (wv.y > v0) + (wv.z > v0) + (wv.w > v0);
            r1 += (wv.x > v1) + (wv.y > v1) + (wv.z > v1) + (wv.w > v1);
            r2 += (wv.x > v2) + (wv.y > v2) + (wv.z > v2) + (wv.w > v2);
        }
        const int task16 = task * TOPK;
        if (r0 < TOPK) {
            sval[task][r0] = v0; sidx[task][r0] = lane;
            const int q = task16 + r0;
            sp4[q][0] = pt[lane * 3 + 0];
            sp4[q][1] = pt[lane * 3 + 1];
            sp4[q][2] = pt[lane * 3 + 2];
            sp4[q][3] = 0.0f;
        }
        if (r1 < TOPK) {
            sval[task][r1] = v1; sidx[task][r1] = lane + 64;
            const int q = task16 + r1;
            sp4[q][0] = pt[(lane + 64) * 3 + 0];
            sp4[q][1] = pt[(lane + 64) * 3 + 1];
            sp4[q][2] = pt[(lane + 64) * 3 + 2];
            sp4[q][3] = 0.0f;
        }
        if (r2 < TOPK) {
            sval[task][r2] = v2; sidx[task][r2] = lane + 128;
            const int q = task16 + r2;
            sp4[q][0] = pt[(lane + 128) * 3 + 0];
            sp4[q][1] = pt[(lane + 128) * 3 + 1];
            sp4[q][2] = pt[(lane + 128) * 3 + 2];
            sp4[q][3] = 0.0f;
        }
    }
    __syncthreads();

    // ---- phase B2: tie repair (only on bit-equal ties; racy-idempotent) ---
    if (wid < 4) {
        const int task = wid;
        const int task16 = task * TOPK;
        #pragma unroll
        for (int k = 0; k < 3; ++k) {
            const int   e  = lane + k * 64;
            const int   rr = (k == 0) ? r0 : (k == 1) ? r1 : r2;
            const float vv = (k == 0) ? v0 : (k == 1) ? v1 : v2;
            if (rr < TOPK && sidx[task][rr] != e) {
                const int surv = sidx[task][rr];
                const int lo_e = (e < surv) ? e : surv;
                const int hi_e = (e < surv) ? surv : e;
                {
                    const int q = task16 + rr;
                    sval[task][rr] = vv; sidx[task][rr] = lo_e;
                    sp4[q][0] = pt[lo_e * 3 + 0];
                    sp4[q][1] = pt[lo_e * 3 + 1];
                    sp4[q][2] = pt[lo_e * 3 + 2];
                    sp4[q][3] = 0.0f;
                }
                if (rr + 1 < TOPK) {
                    const int q = task16 + rr + 1;
                    sval[task][rr + 1] = vv; sidx[task][rr + 1] = hi_e;
                    sp4[q][0] = pt[hi_e * 3 + 0];
                    sp4[q][1] = pt[hi_e * 3 + 1];
                    sp4[q][2] = pt[hi_e * 3 + 2];
                    sp4[q][3] = 0.0f;
                }
            }
        }
    }
    __syncthreads();

    // ---- phase C: renorm + per-task W + bounds (wave 0, lane = q) ----
    if (wid == 0) {
        const int t = lane >> 4;
        const float v = sval[t][lane & 15];
        float s = v;                     // per-16-group (per-task) sum
        s += __shfl_xor(s, 1, 64);
        s += __shfl_xor(s, 2, 64);
        s += __shfl_xor(s, 4, 64);
        s += __shfl_xor(s, 8, 64);
        const float denom = s + 1e-5f;
        sw[lane] = v / denom;
        if ((lane & 15) == 0) sW[t] = s / denom;

        // bounds over all 64 selected points
        const float px = sp4[lane][0], py = sp4[lane][1], pz = sp4[lane][2];
        float nx = px, Xx = px, ny = py, Xy = py, nz = pz, Xz = pz;
        #pragma unroll
        for (int m = 32; m; m >>= 1) {
            nx = fminf(nx, __shfl_xor(nx, m, 64));
            Xx = fmaxf(Xx, __shfl_xor(Xx, m, 64));
            ny = fminf(ny, __shfl_xor(ny, m, 64));
            Xy = fmaxf(Xy, __shfl_xor(Xy, m, 64));
            nz = fminf(nz, __shfl_xor(nz, m, 64));
            Xz = fmaxf(Xz, __shfl_xor(Xz, m, 64));
        }
        if (lane == 0) {
            sbound[0] = nx - 3.0f * SIGMA_F; sbound[3] = Xx + 3.0f * SIGMA_F;
            sbound[1] = ny - 3.0f * SIGMA_F; sbound[4] = Xy + 3.0f * SIGMA_F;
            sbound[2] = nz - 3.0f * SIGMA_F; sbound[5] = Xz + 3.0f * SIGMA_F;
        }
    }
    __syncthreads();

    // ---- phase D: 512 cross-pair Gaussian overlaps, exactly 1/thread ----
    float e;
    {
        const int batch = tid >> 8;
        const int qa = batch * 16 + ((tid >> 4) & 15);        // set1 row
        const int qb = 32 + batch * 16 + (tid & 15);          // set2 row
        const float4 pa = *(const float4*)sp4[qa];
        const float4 pb = *(const float4*)sp4[qb];
        const float dx = pa.x - pb.x;
        const float dy = pa.y - pb.y;
        const float dz = pa.z - pb.z;
        const float D2 = dx * dx + dy * dy + dz * dz;
        const float INV4S2 = 1.0f / (4.0f * SIGMA_F * SIGMA_F);
        e = sw[qa] * sw[qb] * __expf(-D2 * INV4S2);
    }
    #pragma unroll
    for (int m = 32; m; m >>= 1) e += __shfl_xor(e, m, 64);
    if (lane == 0) rP[wid] = e;
    __syncthreads();

    // ---- phase E: finalize ----
    if (tid == 0) {
        float psum = 0.0f;
        #pragma unroll
        for (int w = 0; w < 8; ++w) psum += rP[w];
        const float Dx = (sbound[3] - sbound[0]) * (1.0f / 127.0f);
        const float Dy = (sbound[4] - sbound[1]) * (1.0f / 127.0f);
        const float Dz = (sbound[5] - sbound[2]) * (1.0f / 127.0f);
        const float s3   = SIGMA_F * SIGMA_F * SIGMA_F;
        const float PI15 = 5.5683280f;                 // pi^1.5
        const float KI   = s3 * PI15 / (Dx * Dy * Dz);
        const float KS   = KI * 2.8284271f;            // * 2^1.5
        const float I = KI * psum;
        const float S = KS * ((sW[0] + sW[1]) + (sW[2] + sW[3]));
        const float U = S - I + 1e-5f;
        out[0] = 1.0f - I / U;
    }
}

extern "C" void kernel_launch(void* const* d_in, const int* in_sizes, int n_in,
                              void* d_out, int out_size, void* d_ws, size_t ws_size,
                              hipStream_t stream)
{
    const float* pts1 = (const float*)d_in[0];   // [2,192,3]
    const float* w1   = (const float*)d_in[1];   // [2,192]
    const float* pts2 = (const float*)d_in[2];   // [2,192,3]
    const float* w2   = (const float*)d_in[3];   // [2,192]
    float* out = (float*)d_out;                  // scalar

    iou_analytic<<<1, NTHR, 0, stream>>>(pts1, w1, pts2, w2, out);
}

// Round 15
// 10.541 us; speedup vs baseline: 1.2036x; 1.2036x over previous
//
#include <hip/hip_runtime.h>
#include <math.h>

#define RES 128
#define TOPK 16
#define NPTS 192
#define NQ 64                    // 4 tasks * 16 points
#define SIGMA_F (6.0f / 128.0f)
#define NTHR 768                 // 12 waves: one (task, element) per thread

// ---------------------------------------------------------------------------
// Analytic separable IoU (validated exact-to-threshold R11-R14):
//   I  = KI * sum_{batch,q,q'} w_q w_q' exp(-|pa-pb|^2/(4 sigma^2)),
//   KI = sigma^3 pi^1.5 / (Dx*Dy*Dz);  S1+S2 = KI * 2^1.5 * sum_t W_t
//   U = S1+S2-I+1e-5 ;  loss = 1 - I/U
// R15: revert to the R13 shape (12 waves, 1 element/thread — R14 showed
// width beats per-thread amortization in this latency regime), and move the
// rank-table reads OFF the LDS pipe: weights are read through a
// readfirstlane-forced wave-uniform pointer (HK SGPR-hoist pattern) so the
// backend can emit s_load through the scalar cache. No LDS staging, one
// fewer barrier. Strict rank + deterministic tie repair as in R13.
// task: 0 = set1/b0, 1 = set1/b1, 2 = set2/b0, 3 = set2/b1
// ---------------------------------------------------------------------------
__global__ __launch_bounds__(NTHR) void iou_analytic(
    const float* __restrict__ pts1, const float* __restrict__ w1,
    const float* __restrict__ pts2, const float* __restrict__ w2,
    float* __restrict__ out)
{
    __shared__ float sval[4][TOPK];
    __shared__ int   sidx[4][TOPK];
    __shared__ __align__(16) float sp4[NQ][4];       // xyz + pad
    __shared__ float sw[NQ];
    __shared__ float sW[4];          // per-task sum of renormalized weights
    __shared__ float sbound[6];      // lo x,y,z ; hi x,y,z
    __shared__ float rP[12];

    const int tid  = threadIdx.x;
    const int lane = tid & 63;
    const int wid  = tid >> 6;       // 0..11

    const int task = wid / 3;                       // 3 waves per task
    const int elem = (wid - task * 3) * 64 + lane;  // 0..191
    const float* __restrict__ wt = (task >= 2 ? w2 : w1) + (task & 1) * NPTS;
    const float* __restrict__ pt = (task >= 2 ? pts2 : pts1) + (task & 1) * NPTS * 3;

    // force a wave-uniform (SGPR) copy of the weight-table pointer so the
    // rank loop's uniform-index reads can go through the scalar path
    const float* wt_u;
    {
        const unsigned long long up = (unsigned long long)(uintptr_t)wt;
        const unsigned plo = __builtin_amdgcn_readfirstlane((unsigned)up);
        const unsigned phi = __builtin_amdgcn_readfirstlane((unsigned)(up >> 32));
        wt_u = (const float*)(uintptr_t)(((unsigned long long)phi << 32) | plo);
    }

    // ---- phase B: strict rank among 192 (uniform-address table reads) ----
    const float myv = wt[elem];
    int r = 0;
    {
        const float4* __restrict__ wrow = (const float4*)wt_u;
        #pragma unroll
        for (int c = 0; c < NPTS / 4; ++c) {
            const float4 wv = wrow[c];       // wave-uniform -> scalar load
            r += (wv.x > myv);
            r += (wv.y > myv);
            r += (wv.z > myv);
            r += (wv.w > myv);
        }
        if (r < TOPK) {                      // tentative top-16: publish
            const int q = task * TOPK + r;
            sval[task][r] = myv;
            sidx[task][r] = elem;
            sp4[q][0] = pt[elem * 3 + 0];
            sp4[q][1] = pt[elem * 3 + 1];
            sp4[q][2] = pt[elem * 3 + 2];
            sp4[q][3] = 0.0f;
        }
    }
    __syncthreads();

    // ---- phase B2: tie repair (executes only on bit-equal weight ties) ----
    if (r < TOPK && sidx[task][r] != elem) {
        // lost the scatter race at slot r -> equal-valued partner exists
        const int surv = sidx[task][r];
        const int lo_e = (elem < surv) ? elem : surv;
        const int hi_e = (elem < surv) ? surv : elem;
        {
            const int q = task * TOPK + r;   // slot r: lower index (top_k order)
            sval[task][r] = myv;
            sidx[task][r] = lo_e;
            sp4[q][0] = pt[lo_e * 3 + 0];
            sp4[q][1] = pt[lo_e * 3 + 1];
            sp4[q][2] = pt[lo_e * 3 + 2];
            sp4[q][3] = 0.0f;
        }
        if (r + 1 < TOPK) {                  // next slot: higher index
            const int q = task * TOPK + r + 1;
            sval[task][r + 1] = myv;
            sidx[task][r + 1] = hi_e;
            sp4[q][0] = pt[hi_e * 3 + 0];
            sp4[q][1] = pt[hi_e * 3 + 1];
            sp4[q][2] = pt[hi_e * 3 + 2];
            sp4[q][3] = 0.0f;
        }
    }
    __syncthreads();

    // ---- phase C: renorm + per-task W + bounds (wave 0, lane = q) ----
    if (wid == 0) {
        const int t = lane >> 4;
        const float v = sval[t][lane & 15];
        float s = v;                     // per-16-group (per-task) sum
        s += __shfl_xor(s, 1, 64);
        s += __shfl_xor(s, 2, 64);
        s += __shfl_xor(s, 4, 64);
        s += __shfl_xor(s, 8, 64);
        const float denom = s + 1e-5f;
        sw[lane] = v / denom;
        if ((lane & 15) == 0) sW[t] = s / denom;

        // bounds over all 64 selected points
        const float px = sp4[lane][0], py = sp4[lane][1], pz = sp4[lane][2];
        float nx = px, Xx = px, ny = py, Xy = py, nz = pz, Xz = pz;
        #pragma unroll
        for (int m = 32; m; m >>= 1) {
            nx = fminf(nx, __shfl_xor(nx, m, 64));
            Xx = fmaxf(Xx, __shfl_xor(Xx, m, 64));
            ny = fminf(ny, __shfl_xor(ny, m, 64));
            Xy = fmaxf(Xy, __shfl_xor(Xy, m, 64));
            nz = fminf(nz, __shfl_xor(nz, m, 64));
            Xz = fmaxf(Xz, __shfl_xor(Xz, m, 64));
        }
        if (lane == 0) {
            sbound[0] = nx - 3.0f * SIGMA_F; sbound[3] = Xx + 3.0f * SIGMA_F;
            sbound[1] = ny - 3.0f * SIGMA_F; sbound[4] = Xy + 3.0f * SIGMA_F;
            sbound[2] = nz - 3.0f * SIGMA_F; sbound[5] = Xz + 3.0f * SIGMA_F;
        }
    }
    __syncthreads();

    // ---- phase D: 512 cross-pair Gaussian overlaps (1 per thread) ----
    float e = 0.0f;
    if (tid < 512) {
        const int batch = tid >> 8;
        const int qa = batch * 16 + ((tid >> 4) & 15);        // set1 row
        const int qb = 32 + batch * 16 + (tid & 15);          // set2 row
        const float4 pa = *(const float4*)sp4[qa];
        const float4 pb = *(const float4*)sp4[qb];
        const float dx = pa.x - pb.x;
        const float dy = pa.y - pb.y;
        const float dz = pa.z - pb.z;
        const float D2 = dx * dx + dy * dy + dz * dz;
        const float INV4S2 = 1.0f / (4.0f * SIGMA_F * SIGMA_F);
        e = sw[qa] * sw[qb] * __expf(-D2 * INV4S2);
    }
    #pragma unroll
    for (int m = 32; m; m >>= 1) e += __shfl_xor(e, m, 64);
    if (lane == 0) rP[wid] = e;
    __syncthreads();

    // ---- phase E: finalize ----
    if (tid == 0) {
        float psum = 0.0f;
        #pragma unroll
        for (int w = 0; w < 8; ++w) psum += rP[w];    // waves 8-11 held zeros
        const float Dx = (sbound[3] - sbound[0]) * (1.0f / 127.0f);
        const float Dy = (sbound[4] - sbound[1]) * (1.0f / 127.0f);
        const float Dz = (sbound[5] - sbound[2]) * (1.0f / 127.0f);
        const float s3   = SIGMA_F * SIGMA_F * SIGMA_F;
        const float PI15 = 5.5683280f;                 // pi^1.5
        const float KI   = s3 * PI15 / (Dx * Dy * Dz);
        const float KS   = KI * 2.8284271f;            // * 2^1.5
        const float I = KI * psum;
        const float S = KS * ((sW[0] + sW[1]) + (sW[2] + sW[3]));
        const float U = S - I + 1e-5f;
        out[0] = 1.0f - I / U;
    }
}

extern "C" void kernel_launch(void* const* d_in, const int* in_sizes, int n_in,
                              void* d_out, int out_size, void* d_ws, size_t ws_size,
                              hipStream_t stream)
{
    const float* pts1 = (const float*)d_in[0];   // [2,192,3]
    const float* w1   = (const float*)d_in[1];   // [2,192]
    const float* pts2 = (const float*)d_in[2];   // [2,192,3]
    const float* w2   = (const float*)d_in[3];   // [2,192]
    float* out = (float*)d_out;                  // scalar

    iou_analytic<<<1, NTHR, 0, stream>>>(pts1, w1, pts2, w2, out);
}